// Round 14
// baseline (38.106 us; speedup 1.0000x reference)
//
#include <hip/hip_runtime.h>

#define MM 576
#define NBLK 256
#define NTHR 512

__device__ __forceinline__ float lrelu(float x) { return x > 0.f ? x : 0.2f * x; }
__device__ __forceinline__ float elu1(float x)  { return x > 0.f ? x : (__expf(x) - 1.f); }
__device__ __forceinline__ unsigned short f2bf(float f) {   // RNE
    unsigned u = __float_as_uint(f);
    return (unsigned short)((u + 0x7FFFu + ((u >> 16) & 1u)) >> 16);
}

// ---------------------------------------------------------------------------
// e-partial producer body (k1 and kG0's tail). Block (n,t,s) owns rows
// m = t*144 + s*9 + [0,9), stored contiguously in xb (LDS, fp32).
// Computes Wh on the fly (no store) and reduces the separable logit
// partials to ep[n][q=t][s][256].
// ---------------------------------------------------------------------------
__device__ __forceinline__ void e_body(int n, int t, int s,
                                       const float* __restrict__ xb,   // LDS
                                       float* __restrict__ red,        // LDS
                                       const float* __restrict__ mw_l,
                                       const float* __restrict__ mb_l,
                                       const float* __restrict__ a_l,
                                       float* __restrict__ ep) {
    int tid = threadIdx.x;
    int sub = tid >> 5, v = tid & 31;
    int hd = sub & 3, r0 = sub >> 2;
    float ei = 0.f, ej = 0.f;
    for (int r = r0; r < 9; r += 4) {
        int rr = s * 9 + r;
        int dh = rr / 24, wc = rr % 24;
        const float* ab = a_l + hd * 1152 + dh * 192 + wc * 4;
        float4 aiv = *(const float4*)ab;
        float4 ajv = *(const float4*)(ab + 96);
        float x0 = xb[r * 128 + v],      x1 = xb[r * 128 + 32 + v];
        float x2 = xb[r * 128 + 64 + v], x3 = xb[r * 128 + 96 + v];
#pragma unroll
        for (int tt = 0; tt < 4; ++tt) {
            float wh = fmaf(x0, mw_l[hd * 16 + tt],
                        fmaf(x1, mw_l[hd * 16 + 4 + tt],
                         fmaf(x2, mw_l[hd * 16 + 8 + tt],
                          fmaf(x3, mw_l[hd * 16 + 12 + tt], mb_l[hd * 4 + tt]))));
            ei = fmaf(wh, (&aiv.x)[tt], ei);
            ej = fmaf(wh, (&ajv.x)[tt], ej);
        }
    }
    red[(sub * 2 + 0) * 32 + v] = ei;
    red[(sub * 2 + 1) * 32 + v] = ej;
    __syncthreads();
    if (tid < 256) {        // tid == hd*64 + wh*32 + v
        int hdx = tid >> 6, whx = (tid >> 5) & 1, vx = tid & 31;
        float e = 0.f;
#pragma unroll
        for (int k = 0; k < 4; ++k)
            e += red[((hdx + 4 * k) * 2 + whx) * 32 + vx];
        ep[(((size_t)(n * 4 + t)) * 16 + s) * 256 + tid] = e;
    }
}

// ---------------------------------------------------------------------------
// Whh recompute into LDS (bf16) from the staged slice — identical fmaf
// chain as e_body, so values match the former global-Wh path bit-for-bit.
// ---------------------------------------------------------------------------
__device__ __forceinline__ void wh_to_lds(int s, const float* __restrict__ xb,
                                          const float* __restrict__ mw_l,
                                          const float* __restrict__ mb_l,
                                          unsigned short (*Whh)[4][9][32]) {
    int tid = threadIdx.x;
    int sub = tid >> 5, v = tid & 31;
    int hd = sub & 3, r0 = sub >> 2;
    for (int r = r0; r < 9; r += 4) {
        float x0 = xb[r * 128 + v],      x1 = xb[r * 128 + 32 + v];
        float x2 = xb[r * 128 + 64 + v], x3 = xb[r * 128 + 96 + v];
#pragma unroll
        for (int tt = 0; tt < 4; ++tt) {
            float wh = fmaf(x0, mw_l[hd * 16 + tt],
                        fmaf(x1, mw_l[hd * 16 + 4 + tt],
                         fmaf(x2, mw_l[hd * 16 + 8 + tt],
                          fmaf(x3, mw_l[hd * 16 + 12 + tt], mb_l[hd * 4 + tt]))));
            Whh[hd][tt][r][v] = f2bf(wh);
        }
    }
}

// ---------------------------------------------------------------------------
// k1: stage x slice -> e-partials(L0). No Wh store (kG0 recomputes it).
// ---------------------------------------------------------------------------
__global__ __launch_bounds__(NTHR) void k1(const float* __restrict__ x,
                                           const float* __restrict__ map_w,
                                           const float* __restrict__ map_b,
                                           const float* __restrict__ a_temp,
                                           float* __restrict__ ep0) {
    __shared__ float xb[1152];
    __shared__ float red[1024];
    int b = blockIdx.x, tid = threadIdx.x;
    int n = b >> 6, t = (b >> 4) & 3, s = b & 15;
    if (tid < 288)
        ((float4*)xb)[tid] = ((const float4*)(x + (size_t)b * 1152))[tid];
    __syncthreads();
    e_body(n, t, s, xb, red, map_w, map_b, a_temp, ep0);
}

// ---------------------------------------------------------------------------
// Single-wave adjacency build (fp32, shfl-based; validated R13).
// ---------------------------------------------------------------------------
__device__ __forceinline__ void adj_build_one(const float* __restrict__ B,
                                              float* __restrict__ adjf,
                                              float* __restrict__ d12s) {
    int lane = threadIdx.x & 63;
    int u = lane & 31;
    float val[16], lmin = 1e30f, lmax = -1e30f;
#pragma unroll
    for (int k = 0; k < 16; ++k) {
        int p = lane + 64 * k;
        float vv = B[p] + ((p >> 5) == (p & 31) ? 1.f : 0.f);
        val[k] = vv;
        lmin = fminf(lmin, vv);
        lmax = fmaxf(lmax, vv);
    }
#pragma unroll
    for (int off = 32; off; off >>= 1) {
        lmin = fminf(lmin, __shfl_xor(lmin, off, 64));
        lmax = fmaxf(lmax, __shfl_xor(lmax, off, 64));
    }
    float inv = 1.f / (lmax - lmin);
    float d12r[16];
    int h = lane >> 5;
#pragma unroll
    for (int k = 0; k < 16; ++k) {      // row sum of row 2k+h (half-wave)
        float r = val[k];
#pragma unroll
        for (int off = 16; off; off >>= 1) r += __shfl_xor(r, off, 64);
        float rsn = (r - 32.f * lmin) * inv;
        d12r[k] = rsqrtf(rsn);
        if (u == 2 * k + h) d12s[u] = d12r[k];
    }
#pragma unroll
    for (int k = 0; k < 16; ++k) {      // in-wave LDS write->read, ordered
        int p = lane + 64 * k;
        adjf[p] = (val[k] - lmin) * inv * d12r[k] * d12s[p & 31];
    }
}

// ---------------------------------------------------------------------------
// kC: 64 blocks = (n, hd, q). e-reduce -> adj -> att^T -> C, stored
// transposed: CT[n][hd][q][u][j] fp32.  (validated R13)
// ---------------------------------------------------------------------------
__global__ __launch_bounds__(256) void kC(const float* __restrict__ Bp_l,
                                          const float* __restrict__ ep,
                                          float* __restrict__ CT) {
    __shared__ float e[4][2][32];
    __shared__ float adjf[1024];
    __shared__ float attT[32 * 33];
    __shared__ float d12s[32];
    int b = blockIdx.x, tid = threadIdx.x;
    int n = b >> 4, hd = (b >> 2) & 3, q = b & 3;

    {   // e-reduce over 16 s-slices: thread -> (q', wh, v)
        int qp = tid >> 6, rest = tid & 63;
        const float* src = ep + ((size_t)(n * 4 + qp) * 16) * 256 + hd * 64 + rest;
        float a = 0.f;
#pragma unroll
        for (int ss = 0; ss < 16; ++ss) a += src[ss * 256];
        e[qp][rest >> 5][rest & 31] = a;
    }
    if (tid < 64) adj_build_one(Bp_l + (size_t)hd * 1024, adjf, d12s);
    __syncthreads();

    {   // att^T[j][i], softmax over q' keeping q
        int i = tid & 31;
        float ei0 = e[0][0][i], ei1 = e[1][0][i], ei2 = e[2][0][i], ei3 = e[3][0][i];
#pragma unroll
        for (int k = 0; k < 4; ++k) {
            int j = (tid + 256 * k) >> 5;
            float eq0 = lrelu(ei0 + e[0][1][j]);
            float eq1 = lrelu(ei1 + e[1][1][j]);
            float eq2 = lrelu(ei2 + e[2][1][j]);
            float eq3 = lrelu(ei3 + e[3][1][j]);
            float mx = fmaxf(fmaxf(eq0, eq1), fmaxf(eq2, eq3));
            eq0 = __expf(eq0 - mx); eq1 = __expf(eq1 - mx);
            eq2 = __expf(eq2 - mx); eq3 = __expf(eq3 - mx);
            float invs = __builtin_amdgcn_rcpf(eq0 + eq1 + eq2 + eq3);
            float num = (q & 2) ? ((q & 1) ? eq3 : eq2) : ((q & 1) ? eq1 : eq0);
            attT[j * 33 + i] = num * invs;
        }
    }
    __syncthreads();

    {   // CT[u][j4..j4+3] = C[j][u] = sum_i attT[j][i] * adjf[i][u]
        int u = tid >> 3, j4 = (tid & 7) * 4;
        float c0 = 0.f, c1 = 0.f, c2 = 0.f, c3 = 0.f;
#pragma unroll
        for (int i = 0; i < 32; ++i) {
            float ad = adjf[i * 32 + u];
            c0 = fmaf(attT[(j4 + 0) * 33 + i], ad, c0);
            c1 = fmaf(attT[(j4 + 1) * 33 + i], ad, c1);
            c2 = fmaf(attT[(j4 + 2) * 33 + i], ad, c2);
            c3 = fmaf(attT[(j4 + 3) * 33 + i], ad, c3);
        }
        *(float4*)&CT[(((size_t)(n * 4 + hd) * 4 + q) * 32 + (tid >> 3)) * 32 + j4] =
            make_float4(c0, c1, c2, c3);
    }
}

// ---------------------------------------------------------------------------
// kG: 256 blocks = (n,t,s). Stage source slice (x or inter: both are the
// contiguous b*1152 floats), recompute Whh in LDS (overlapped with cc
// prefetch), gemm + elu + head-mean. LAST ? out : {store inter rows, tail
// e-partials for layer 2}.
// ---------------------------------------------------------------------------
template<bool LAST>
__device__ __forceinline__ void kG_body(const float* __restrict__ src,
                                        const float* __restrict__ CT,
                                        const float* __restrict__ mw_l,
                                        const float* __restrict__ mb_l,
                                        const float* __restrict__ mw2,
                                        const float* __restrict__ mb2,
                                        const float* __restrict__ a2,
                                        float* __restrict__ interg,
                                        float* __restrict__ ep_out,
                                        float* __restrict__ outg) {
    __shared__ unsigned short Whh[4][4][9][32];   // 9216 B
    __shared__ float uf[3584];  // [0,1152) xb | [1216,2240) red | [2304,3584) partials
    int b = blockIdx.x, tid = threadIdx.x;
    int n = b >> 6, t = (b >> 4) & 3, s = b & 15;
    int w = tid >> 6, lane = tid & 63;
    int g = w >> 2, tout = w & 3;
    int u = lane & 31, h = lane >> 5;

    // stage source slice
    if (tid < 288)
        ((float4*)uf)[tid] = ((const float4*)(src + (size_t)b * 1152))[tid];
    // prefetch C columns for both hd of this wave's group (independent of LDS)
    float cc0[32], cc1[32];
    const float4* ct0 = (const float4*)(CT + (((size_t)(n * 4 + 2 * g) * 4 + tout) * 32 + u) * 32);
    const float4* ct1 = (const float4*)(CT + (((size_t)(n * 4 + 2 * g + 1) * 4 + tout) * 32 + u) * 32);
#pragma unroll
    for (int k = 0; k < 8; ++k) *(float4*)&cc0[4 * k] = ct0[k];
#pragma unroll
    for (int k = 0; k < 8; ++k) *(float4*)&cc1[4 * k] = ct1[k];
    __syncthreads();
    wh_to_lds(s, uf, mw_l, mb_l, Whh);      // recompute Wh (bit-identical)
    __syncthreads();

    float acc[5] = {0.f, 0.f, 0.f, 0.f, 0.f};
    auto gemm_hd = [&](int hd, const float (&cc)[32]) {
#pragma unroll
        for (int k = 0; k < 5; ++k) {
            int r = h ? (k < 4 ? 5 + k : 8) : k;   // k==4,h==1 discarded
            const uint4* wr = (const uint4*)&Whh[hd][tout][r][0];
            float d = 0.f;
#pragma unroll
            for (int q4 = 0; q4 < 4; ++q4) {
                uint4 pk = wr[q4];
                d = fmaf(__uint_as_float(pk.x << 16),         cc[8 * q4 + 0], d);
                d = fmaf(__uint_as_float(pk.x & 0xFFFF0000u), cc[8 * q4 + 1], d);
                d = fmaf(__uint_as_float(pk.y << 16),         cc[8 * q4 + 2], d);
                d = fmaf(__uint_as_float(pk.y & 0xFFFF0000u), cc[8 * q4 + 3], d);
                d = fmaf(__uint_as_float(pk.z << 16),         cc[8 * q4 + 4], d);
                d = fmaf(__uint_as_float(pk.z & 0xFFFF0000u), cc[8 * q4 + 5], d);
                d = fmaf(__uint_as_float(pk.w << 16),         cc[8 * q4 + 6], d);
                d = fmaf(__uint_as_float(pk.w & 0xFFFF0000u), cc[8 * q4 + 7], d);
            }
            acc[k] += elu1(d);
        }
    };
    gemm_hd(2 * g,     cc0);
    gemm_hd(2 * g + 1, cc1);

    if (g == 1) {       // publish partials
        float* part = uf + 2304 + tout * 320;
#pragma unroll
        for (int k = 0; k < 5; ++k)
            if (h == 0 || k < 4) part[k * 64 + lane] = acc[k];
    }
    __syncthreads();
    if (g == 0) {
        const float* part = uf + 2304 + tout * 320;
#pragma unroll
        for (int k = 0; k < 5; ++k)
            if (h == 0 || k < 4) acc[k] += part[k * 64 + lane];
        if (LAST) {
            size_t mb = (size_t)(n * MM + t * 144 + s * 9);
#pragma unroll
            for (int k = 0; k < 5; ++k) {
                if (h == 0 || k < 4) {
                    int r = h ? 5 + k : k;
                    outg[((mb + r) * 4 + tout) * 32 + u] = 0.25f * acc[k];
                }
            }
        } else {        // layer-boundary rows stay in LDS (overwrite staged x)
#pragma unroll
            for (int k = 0; k < 5; ++k) {
                if (h == 0 || k < 4) {
                    int r = h ? 5 + k : k;
                    uf[r * 128 + tout * 32 + u] = 0.25f * acc[k];
                }
            }
        }
    }

    if (!LAST) {
        __syncthreads();    // inter rows complete in uf
        if (tid < 288)      // spill inter for kG1 (fp32, block-contiguous)
            ((float4*)(interg + (size_t)b * 1152))[tid] = ((const float4*)uf)[tid];
        e_body(n, t, s, uf, uf + 1216, mw2, mb2, a2, ep_out);
    }
}

__global__ __launch_bounds__(NTHR) void kG0(const float* __restrict__ x,
                                            const float* __restrict__ CT,
                                            const float* __restrict__ mw1,
                                            const float* __restrict__ mb1,
                                            const float* __restrict__ mw2,
                                            const float* __restrict__ mb2,
                                            const float* __restrict__ a2,
                                            float* __restrict__ interg,
                                            float* __restrict__ ep1) {
    kG_body<false>(x, CT, mw1, mb1, mw2, mb2, a2, interg, ep1, nullptr);
}

__global__ __launch_bounds__(NTHR) void kG1(const float* __restrict__ interg,
                                            const float* __restrict__ CT,
                                            const float* __restrict__ mw2,
                                            const float* __restrict__ mb2,
                                            float* __restrict__ outg) {
    kG_body<true>(interg, CT, mw2, mb2, nullptr, nullptr, nullptr,
                  nullptr, nullptr, outg);
}

// ---------------------------------------------------------------------------
extern "C" void kernel_launch(void* const* d_in, const int* in_sizes, int n_in,
                              void* d_out, int out_size, void* d_ws, size_t ws_size,
                              hipStream_t stream) {
    const float* x      = (const float*)d_in[0];
    const float* map_w  = (const float*)d_in[1];
    const float* map_b  = (const float*)d_in[2];
    const float* a_temp = (const float*)d_in[3];
    const float* Bp     = (const float*)d_in[4];
    float* out = (float*)d_out;

    float* ep0    = (float*)d_ws;           //  65536 f
    float* ep1    = ep0 + 65536;            //  65536 f
    float* CT0    = ep1 + 65536;            //  65536 f
    float* CT1    = CT0 + 65536;            //  65536 f
    float* interg = CT1 + 65536;            // 294912 f
    // Every byte of ep0/ep1/CT0/CT1/interg is overwritten before it is read
    // each call: no memset, no atomics — coherence via kernel boundaries.

    k1 <<<NBLK, NTHR, 0, stream>>>(x, map_w, map_b, a_temp, ep0);
    kC <<<64, 256, 0, stream>>>(Bp, ep0, CT0);
    kG0<<<NBLK, NTHR, 0, stream>>>(x, CT0, map_w, map_b,
                                   map_w + 64, map_b + 16, a_temp + 4608,
                                   interg, ep1);
    kC <<<64, 256, 0, stream>>>(Bp + 4096, ep1, CT1);
    kG1<<<NBLK, NTHR, 0, stream>>>(interg, CT1, map_w + 64, map_b + 16, out);
}

// Round 16
// 36.991 us; speedup vs baseline: 1.0301x; 1.0301x over previous
//
#include <hip/hip_runtime.h>

#define MM 576
#define NBLK 256
#define NTHR 512

__device__ __forceinline__ float lrelu(float x) { return x > 0.f ? x : 0.2f * x; }
__device__ __forceinline__ float elu1(float x)  { return x > 0.f ? x : (__expf(x) - 1.f); }
__device__ __forceinline__ unsigned short f2bf(float f) {   // RNE
    unsigned u = __float_as_uint(f);
    return (unsigned short)((u + 0x7FFFu + ((u >> 16) & 1u)) >> 16);
}

// ---------------------------------------------------------------------------
// Wh + e-partial producer body (K1 and kG0's tail). Block (n,t,s) owns rows
// m = t*144 + s*9 + [0,9). Wh -> Whg[b*4608] bf16; e-partials ->
// ep[n][q=t][s][256].  (validated R12/R13)
// ---------------------------------------------------------------------------
__device__ __forceinline__ void wh_e_body(int n, int t, int s, int b,
                                          const float* __restrict__ xb,   // LDS
                                          float* __restrict__ red,        // LDS
                                          const float* __restrict__ mw_l,
                                          const float* __restrict__ mb_l,
                                          const float* __restrict__ a_l,
                                          unsigned short* __restrict__ Whg,
                                          float* __restrict__ ep) {
    int tid = threadIdx.x;
    int sub = tid >> 5, v = tid & 31;
    int hd = sub & 3, r0 = sub >> 2;
    unsigned short* Wb = Whg + (size_t)b * 4608;
    float ei = 0.f, ej = 0.f;
    for (int r = r0; r < 9; r += 4) {
        int rr = s * 9 + r;
        int dh = rr / 24, wc = rr % 24;
        const float* ab = a_l + hd * 1152 + dh * 192 + wc * 4;
        float4 aiv = *(const float4*)ab;
        float4 ajv = *(const float4*)(ab + 96);
        float x0 = xb[r * 128 + v],      x1 = xb[r * 128 + 32 + v];
        float x2 = xb[r * 128 + 64 + v], x3 = xb[r * 128 + 96 + v];
#pragma unroll
        for (int tt = 0; tt < 4; ++tt) {
            float wh = fmaf(x0, mw_l[hd * 16 + tt],
                        fmaf(x1, mw_l[hd * 16 + 4 + tt],
                         fmaf(x2, mw_l[hd * 16 + 8 + tt],
                          fmaf(x3, mw_l[hd * 16 + 12 + tt], mb_l[hd * 4 + tt]))));
            Wb[((hd * 4 + tt) * 9 + r) * 32 + v] = f2bf(wh);
            ei = fmaf(wh, (&aiv.x)[tt], ei);
            ej = fmaf(wh, (&ajv.x)[tt], ej);
        }
    }
    red[(sub * 2 + 0) * 32 + v] = ei;
    red[(sub * 2 + 1) * 32 + v] = ej;
    __syncthreads();
    if (tid < 256) {        // tid == hd*64 + wh*32 + v
        int hdx = tid >> 6, whx = (tid >> 5) & 1, vx = tid & 31;
        float e = 0.f;
#pragma unroll
        for (int k = 0; k < 4; ++k)
            e += red[((hdx + 4 * k) * 2 + whx) * 32 + vx];
        ep[(((size_t)(n * 4 + t)) * 16 + s) * 256 + tid] = e;
    }
}

// ---------------------------------------------------------------------------
// K1: stage x slice -> Wh(L0) + e-partials(L0).  (validated R12/R13)
// ---------------------------------------------------------------------------
__global__ __launch_bounds__(NTHR) void k1(const float* __restrict__ x,
                                           const float* __restrict__ map_w,
                                           const float* __restrict__ map_b,
                                           const float* __restrict__ a_temp,
                                           unsigned short* __restrict__ Whg,
                                           float* __restrict__ ep0) {
    __shared__ float xb[1152];
    __shared__ float red[1024];
    int b = blockIdx.x, tid = threadIdx.x;
    int n = b >> 6, t = (b >> 4) & 3, s = b & 15;
    if (tid < 288)
        ((float4*)xb)[tid] =
            ((const float4*)(x + (size_t)(n * MM + t * 144 + s * 9) * 128))[tid];
    __syncthreads();
    wh_e_body(n, t, s, b, xb, red, map_w, map_b, a_temp, Whg, ep0);
}

// ---------------------------------------------------------------------------
// Single-wave adjacency build (fp32, shfl-based; validated R13).
// ---------------------------------------------------------------------------
__device__ __forceinline__ void adj_build_one(const float* __restrict__ B,
                                              float* __restrict__ adjf,
                                              float* __restrict__ d12s) {
    int lane = threadIdx.x & 63;
    int u = lane & 31;
    float val[16], lmin = 1e30f, lmax = -1e30f;
#pragma unroll
    for (int k = 0; k < 16; ++k) {
        int p = lane + 64 * k;
        float vv = B[p] + ((p >> 5) == (p & 31) ? 1.f : 0.f);
        val[k] = vv;
        lmin = fminf(lmin, vv);
        lmax = fmaxf(lmax, vv);
    }
#pragma unroll
    for (int off = 32; off; off >>= 1) {
        lmin = fminf(lmin, __shfl_xor(lmin, off, 64));
        lmax = fmaxf(lmax, __shfl_xor(lmax, off, 64));
    }
    float inv = 1.f / (lmax - lmin);
    float d12r[16];
    int h = lane >> 5;
#pragma unroll
    for (int k = 0; k < 16; ++k) {      // row sum of row 2k+h (half-wave)
        float r = val[k];
#pragma unroll
        for (int off = 16; off; off >>= 1) r += __shfl_xor(r, off, 64);
        float rsn = (r - 32.f * lmin) * inv;
        d12r[k] = rsqrtf(rsn);
        if (u == 2 * k + h) d12s[u] = d12r[k];
    }
#pragma unroll
    for (int k = 0; k < 16; ++k) {      // in-wave LDS write->read, ordered
        int p = lane + 64 * k;
        adjf[p] = (val[k] - lmin) * inv * d12r[k] * d12s[p & 31];
    }
}

// ---------------------------------------------------------------------------
// kC: 64 blocks = (n, hd, q). e-reduce -> adj(fp32) -> att^T(fp32, padded)
// -> C, stored TRANSPOSED to CT[n][hd][q][u][j] (fp32, global/L2).
// Computed once instead of 64x per n.  (validated R13)
// ---------------------------------------------------------------------------
__global__ __launch_bounds__(256) void kC(const float* __restrict__ Bp_l,
                                          const float* __restrict__ ep,
                                          float* __restrict__ CT) {
    __shared__ float e[4][2][32];
    __shared__ float adjf[1024];
    __shared__ float attT[32 * 33];     // +1 pad: conflict-free column reads
    __shared__ float d12s[32];
    int b = blockIdx.x, tid = threadIdx.x;
    int n = b >> 4, hd = (b >> 2) & 3, q = b & 3;

    {   // e-reduce over 16 s-slices: thread -> (q', wh, v)
        int qp = tid >> 6, rest = tid & 63;
        const float* src = ep + ((size_t)(n * 4 + qp) * 16) * 256 + hd * 64 + rest;
        float a = 0.f;
#pragma unroll
        for (int ss = 0; ss < 16; ++ss) a += src[ss * 256];
        e[qp][rest >> 5][rest & 31] = a;
    }
    if (tid < 64) adj_build_one(Bp_l + (size_t)hd * 1024, adjf, d12s);
    __syncthreads();

    {   // att^T[j][i], softmax over q' keeping q
        int i = tid & 31;
        float ei0 = e[0][0][i], ei1 = e[1][0][i], ei2 = e[2][0][i], ei3 = e[3][0][i];
#pragma unroll
        for (int k = 0; k < 4; ++k) {
            int j = (tid + 256 * k) >> 5;
            float eq0 = lrelu(ei0 + e[0][1][j]);
            float eq1 = lrelu(ei1 + e[1][1][j]);
            float eq2 = lrelu(ei2 + e[2][1][j]);
            float eq3 = lrelu(ei3 + e[3][1][j]);
            float mx = fmaxf(fmaxf(eq0, eq1), fmaxf(eq2, eq3));
            eq0 = __expf(eq0 - mx); eq1 = __expf(eq1 - mx);
            eq2 = __expf(eq2 - mx); eq3 = __expf(eq3 - mx);
            float invs = __builtin_amdgcn_rcpf(eq0 + eq1 + eq2 + eq3);
            float num = (q & 2) ? ((q & 1) ? eq3 : eq2) : ((q & 1) ? eq1 : eq0);
            attT[j * 33 + i] = num * invs;
        }
    }
    __syncthreads();

    {   // CT[u][j4..j4+3] = C[j][u] = sum_i attT[j][i] * adjf[i][u]
        int u = tid >> 3, j4 = (tid & 7) * 4;
        float c0 = 0.f, c1 = 0.f, c2 = 0.f, c3 = 0.f;
#pragma unroll
        for (int i = 0; i < 32; ++i) {
            float ad = adjf[i * 32 + u];
            c0 = fmaf(attT[(j4 + 0) * 33 + i], ad, c0);
            c1 = fmaf(attT[(j4 + 1) * 33 + i], ad, c1);
            c2 = fmaf(attT[(j4 + 2) * 33 + i], ad, c2);
            c3 = fmaf(attT[(j4 + 3) * 33 + i], ad, c3);
        }
        *(float4*)&CT[(((size_t)(n * 4 + hd) * 4 + q) * 32 + u) * 32 + j4] =
            make_float4(c0, c1, c2, c3);
    }
}

// ---------------------------------------------------------------------------
// kG: 256 blocks = (n,t,s). cc columns prefetched from CT (global float4),
// Whh copied to LDS (overlapped), gemm + elu + head-mean. LAST ? out :
// (xb -> layer-2 Wh + e-partials via wh_e_body, block-local).
// ---------------------------------------------------------------------------
template<bool LAST>
__device__ __forceinline__ void kG_body(const float* __restrict__ CT,
                                        unsigned short* __restrict__ Whg,
                                        const float* __restrict__ mw2,
                                        const float* __restrict__ mb2,
                                        const float* __restrict__ a2,
                                        float* __restrict__ ep_out,
                                        float* __restrict__ outg) {
    __shared__ unsigned short Whh[4][4][9][32];   // 9216 B
    __shared__ float uf[3584];  // [0,1152) xb | [1216,2240) red | [2304,3584) partials
    int b = blockIdx.x, tid = threadIdx.x;
    int n = b >> 6, t = (b >> 4) & 3, s = b & 15;
    int w = tid >> 6, lane = tid & 63;
    int g = w >> 2, tout = w & 3;
    int u = lane & 31, h = lane >> 5;

    // prefetch C columns for both hd of this wave's group (overlaps copy)
    float cc0[32], cc1[32];
    const float4* ct0 = (const float4*)(CT + (((size_t)(n * 4 + 2 * g) * 4 + tout) * 32 + u) * 32);
    const float4* ct1 = (const float4*)(CT + (((size_t)(n * 4 + 2 * g + 1) * 4 + tout) * 32 + u) * 32);
#pragma unroll
    for (int k = 0; k < 8; ++k) *(float4*)&cc0[4 * k] = ct0[k];
    {   // Whh copy: 2304 u32
        const unsigned* src = (const unsigned*)(Whg + (size_t)b * 4608);
        unsigned* dst = (unsigned*)&Whh[0][0][0][0];
#pragma unroll
        for (int k = 0; k < 4; ++k) dst[tid + 512 * k] = src[tid + 512 * k];
        if (tid < 256) dst[tid + 2048] = src[tid + 2048];
    }
#pragma unroll
    for (int k = 0; k < 8; ++k) *(float4*)&cc1[4 * k] = ct1[k];
    __syncthreads();

    float acc[5] = {0.f, 0.f, 0.f, 0.f, 0.f};
    auto gemm_hd = [&](int hd, const float (&cc)[32]) {
#pragma unroll
        for (int k = 0; k < 5; ++k) {
            int r = h ? (k < 4 ? 5 + k : 8) : k;   // k==4,h==1 discarded
            const uint4* wr = (const uint4*)&Whh[hd][tout][r][0];
            float d = 0.f;
#pragma unroll
            for (int q4 = 0; q4 < 4; ++q4) {
                uint4 pk = wr[q4];
                d = fmaf(__uint_as_float(pk.x << 16),         cc[8 * q4 + 0], d);
                d = fmaf(__uint_as_float(pk.x & 0xFFFF0000u), cc[8 * q4 + 1], d);
                d = fmaf(__uint_as_float(pk.y << 16),         cc[8 * q4 + 2], d);
                d = fmaf(__uint_as_float(pk.y & 0xFFFF0000u), cc[8 * q4 + 3], d);
                d = fmaf(__uint_as_float(pk.z << 16),         cc[8 * q4 + 4], d);
                d = fmaf(__uint_as_float(pk.z & 0xFFFF0000u), cc[8 * q4 + 5], d);
                d = fmaf(__uint_as_float(pk.w << 16),         cc[8 * q4 + 6], d);
                d = fmaf(__uint_as_float(pk.w & 0xFFFF0000u), cc[8 * q4 + 7], d);
            }
            acc[k] += elu1(d);
        }
    };
    gemm_hd(2 * g,     cc0);
    gemm_hd(2 * g + 1, cc1);

    if (g == 1) {       // publish partials
        float* part = uf + 2304 + tout * 320;
#pragma unroll
        for (int k = 0; k < 5; ++k)
            if (h == 0 || k < 4) part[k * 64 + lane] = acc[k];
    }
    __syncthreads();
    if (g == 0) {
        const float* part = uf + 2304 + tout * 320;
#pragma unroll
        for (int k = 0; k < 5; ++k)
            if (h == 0 || k < 4) acc[k] += part[k * 64 + lane];
        if (LAST) {
            size_t mb = (size_t)(n * MM + t * 144 + s * 9);
#pragma unroll
            for (int k = 0; k < 5; ++k) {
                if (h == 0 || k < 4) {
                    int r = h ? 5 + k : k;
                    outg[((mb + r) * 4 + tout) * 32 + u] = 0.25f * acc[k];
                }
            }
        } else {
            float* xb = uf;
#pragma unroll
            for (int k = 0; k < 5; ++k) {
                if (h == 0 || k < 4) {
                    int r = h ? 5 + k : k;
                    xb[r * 128 + tout * 32 + u] = 0.25f * acc[k];
                }
            }
        }
    }

    if (!LAST) {        // layer-2 producer, block-local
        __syncthreads();    // xb complete
        wh_e_body(n, t, s, b, uf, uf + 1216, mw2, mb2, a2, Whg, ep_out);
    }
}

__global__ __launch_bounds__(NTHR) void kG0(const float* __restrict__ CT,
                                            unsigned short* __restrict__ Whg,
                                            const float* __restrict__ mw2,
                                            const float* __restrict__ mb2,
                                            const float* __restrict__ a2,
                                            float* __restrict__ ep1) {
    kG_body<false>(CT, Whg, mw2, mb2, a2, ep1, nullptr);
}

__global__ __launch_bounds__(NTHR) void kG1(const float* __restrict__ CT,
                                            unsigned short* __restrict__ Whg,
                                            float* __restrict__ outg) {
    kG_body<true>(CT, Whg, nullptr, nullptr, nullptr, nullptr, outg);
}

// ---------------------------------------------------------------------------
extern "C" void kernel_launch(void* const* d_in, const int* in_sizes, int n_in,
                              void* d_out, int out_size, void* d_ws, size_t ws_size,
                              hipStream_t stream) {
    const float* x      = (const float*)d_in[0];
    const float* map_w  = (const float*)d_in[1];
    const float* map_b  = (const float*)d_in[2];
    const float* a_temp = (const float*)d_in[3];
    const float* Bp     = (const float*)d_in[4];
    float* out = (float*)d_out;

    unsigned short* Whg = (unsigned short*)d_ws;            // 2,359,296 B
    float* ep0 = (float*)((char*)d_ws + 2359296);           // 65536 f
    float* ep1 = ep0 + 65536;                               // 65536 f
    float* CT0 = ep1 + 65536;                               // 65536 f
    float* CT1 = CT0 + 65536;                               // 65536 f
    // Every byte of Whg/ep0/ep1/CT0/CT1 is overwritten before it is read
    // each call: no memset, no atomics — coherence via kernel boundaries.

    k1 <<<NBLK, NTHR, 0, stream>>>(x, map_w, map_b, a_temp, Whg, ep0);
    kC <<<64, 256, 0, stream>>>(Bp, ep0, CT0);
    kG0<<<NBLK, NTHR, 0, stream>>>(CT0, Whg, map_w + 64, map_b + 16,
                                   a_temp + 4608, ep1);
    kC <<<64, 256, 0, stream>>>(Bp + 4096, ep1, CT1);
    kG1<<<NBLK, NTHR, 0, stream>>>(CT1, Whg, out);
}